// Round 7
// baseline (1182.180 us; speedup 1.0000x reference)
//
#include <hip/hip_runtime.h>
#include <hip/hip_bf16.h>
#include <cstdint>
#include <cstddef>

typedef _Float16 half8 __attribute__((ext_vector_type(8)));
typedef _Float16 half4 __attribute__((ext_vector_type(4)));
typedef float floatx4 __attribute__((ext_vector_type(4)));
typedef unsigned long long u64;

#define B_ 256
#define T_ 168
#define H_ 1024
#define WS_ 64
#define LAG_ 168
#define LAT_ 128
#define SENT 0xFFFFFFFFFFFFFFFFull

__device__ __forceinline__ float fast_sigmoid(float x) {
    return __builtin_amdgcn_rcpf(1.f + __expf(-x));
}
__device__ __forceinline__ float fast_tanh(float x) {
    return 1.f - 2.f * __builtin_amdgcn_rcpf(__expf(2.f * x) + 1.f);
}

// ---------------- fp32 -> fp16 conversion (merged: 3 buffers, 1 launch) ----
__global__ void cvt_all(const float4* __restrict__ a, half4* __restrict__ da, int na,
                        const float4* __restrict__ b, half4* __restrict__ db, int nb,
                        const float4* __restrict__ c, half4* __restrict__ dc, int nc) {
    int i = blockIdx.x * blockDim.x + threadIdx.x;
    const float4* s;
    half4* d;
    int j = i;
    if (j < na) { s = a; d = da; }
    else {
        j -= na;
        if (j < nb) { s = b; d = db; }
        else {
            j -= nb;
            if (j >= nc) return;
            s = c; d = dc;
        }
    }
    float4 v = s[j];
    half4 o;
    o[0] = (_Float16)v.x; o[1] = (_Float16)v.y;
    o[2] = (_Float16)v.z; o[3] = (_Float16)v.w;
    d[j] = o;
}

// ---------------- fused encoder: lag -> 64 -> 128 -> 1024 (one kernel) -----
__global__ void enc_fused(const float* __restrict__ lag,
                          const float* __restrict__ W1, const float* __restrict__ b1,
                          const float* __restrict__ W2, const float* __restrict__ b2,
                          const float* __restrict__ W3, const float* __restrict__ b3,
                          float* __restrict__ hprev32, _Float16* __restrict__ h0f16) {
    __shared__ float lrow[LAG_];
    __shared__ float l1[64];
    __shared__ float l2[LAT_];
    const int r = blockIdx.x, tid = threadIdx.x;
    if (tid < LAG_) lrow[tid] = lag[(size_t)r * LAG_ + tid];
    __syncthreads();
    if (tid < 64) {
        const float* w = W1 + (size_t)tid * LAG_;
        float s = b1[tid];
        for (int k = 0; k < LAG_; ++k) s += lrow[k] * w[k];
        l1[tid] = (s >= 0.f) ? s : 0.01f * s;
    }
    __syncthreads();
    if (tid < LAT_) {
        const float* w = W2 + (size_t)tid * 64;
        float s = b2[tid];
        for (int k = 0; k < 64; ++k) s += l1[k] * w[k];
        l2[tid] = (s >= 0.f) ? s : 0.01f * s;
    }
    __syncthreads();
    for (int j = tid; j < H_; j += 256) {
        const float* w = W3 + (size_t)j * LAT_;
        float acc = b3[j];
        #pragma unroll 8
        for (int k = 0; k < LAT_; ++k) acc += l2[k] * w[k];
        hprev32[(size_t)r * H_ + j] = acc;
        h0f16[(size_t)r * H_ + j]   = (_Float16)acc;
    }
}

// ---------------- R16: 4-phase pipelined GRU with sentinel signaling -------
// R13 (4-phase + flags, 698us) beat R14/R15 single-phase (803/865): phases
// absorb producer jitter (consume fast producers early) and hide each phase's
// load flight under the previous phase's MFMA. R15 proved sentinel mechanics
// correct (data-as-flag, 169-slot ring, no drain/flag/end-barrier). R16 keeps
// R13's loop VERBATIM and swaps signaling: the phase-g staged load IS the
// poll; verify (u64 != 0xFF..F poison, unreachable for finite f16 h) lazily
// right before the phase-g LDS write; producer publish is fire-and-forget.
// Removes ~2 MALL RTTs/step (producer drain + flag store->poll visibility).
// Hazards: phase chunks disjoint + 4 uniform barriers/step; Ash[2] per-step
// double buffer isolates cross-step skew; Hsh is per-wave-private (w<<8
// segment) so the missing end barrier is safe; ring is acyclic (no reuse, no
// re-poison) so deadlock is impossible. R9 fix retained: __threadfence_block
// between Hsh f16 transpose-writes and the u64 publish-read.
__global__ __launch_bounds__(256, 1) void gru_sentinel(
    _Float16* __restrict__ hring,
    const float* __restrict__ hprev32, const _Float16* __restrict__ whh16,
    const _Float16* __restrict__ wih16, const _Float16* __restrict__ x16,
    const float* __restrict__ bih, const float* __restrict__ bhh,
    const float* __restrict__ Wo, float* __restrict__ partials)
{
    __shared__ __align__(16) _Float16 Ash[2][16 * 1032];
    __shared__ __align__(16) _Float16 Wsh[192 * 72];
    __shared__ __align__(16) _Float16 Hsh[4 * 256];

    const int tid  = threadIdx.x;
    const int w    = tid >> 6;
    const int lane = tid & 63;
    const int m16  = lane & 15;
    const int quad = lane >> 4;
    const int pi   = blockIdx.x & 15;
    const int qi   = blockIdx.x >> 4;
    const int pi16 = pi << 4;
    const int u    = (qi << 6) + (w << 4) + m16;

    // Wih slice -> LDS (once)
    for (int idx = tid; idx < 1536; idx += 256) {
        int rowl = idx >> 3, ch = idx & 7;
        int g = rowl >> 6, ru = rowl & 63;
        *(uint4*)(&Wsh[rowl * 72 + (ch << 3)]) =
            *(const uint4*)(wih16 + (size_t)(((g << 10) + (qi << 6) + ru) << 6) + (ch << 3));
    }

    // Resident Whh: r,z gates (AGPR-backed); n streamed per phase (R13 regs)
    half8 br[32], bz[32];
    {
        const _Float16* p0 = whh16 + ((size_t)u << 10) + (quad << 3);
        const _Float16* p1 = whh16 + ((size_t)(H_ + u) << 10) + (quad << 3);
        #pragma unroll
        for (int c = 0; c < 32; ++c) br[c] = *(const half8*)(p0 + (c << 5));
        #pragma unroll
        for (int c = 0; c < 32; ++c) bz[c] = *(const half8*)(p1 + (c << 5));
    }
    const _Float16* bnp = whh16 + ((size_t)(2 * H_ + u) << 10) + (quad << 3);

    const float b_r  = bih[u]          + bhh[u];
    const float b_z  = bih[H_ + u]     + bhh[H_ + u];
    const float b_in = bih[2 * H_ + u];
    const float b_hn = bhh[2 * H_ + u];
    const float wo_u = Wo[u];

    float hreg[4];
    #pragma unroll
    for (int i = 0; i < 4; ++i)
        hreg[i] = hprev32[((size_t)(pi16 + (quad << 2) + i) << 10) + u];

    __syncthreads();

    const int srow = tid >> 4;     // staging: this thread's local row
    const int sch  = tid & 15;     // 32B chunk (16 units)
    const int prow = lane >> 2;    // publish: row, 8B chunk
    const int pc4  = lane & 3;

    for (int t = 0; t < T_; ++t) {
        const _Float16* hsrc = hring + (size_t)t * (B_ * H_);
        _Float16*       hdst = hring + (size_t)(t + 1) * (B_ * H_);

        // h-independent prefetch
        half8 ax0 = *(const half8*)(x16 + (((size_t)t << 8) + pi16 + m16) * WS_ + (quad << 3));
        half8 ax1 = *(const half8*)(x16 + (((size_t)t << 8) + pi16 + m16) * WS_ + 32 + (quad << 3));
        half8 bnA[8], bnB[8];
        #pragma unroll
        for (int j = 0; j < 8; ++j) bnA[j] = *(const half8*)(bnp + (j << 5));

        const _Float16* sbase = hsrc + ((size_t)(pi16 + srow) << 10) + (sch << 4);

        // issue phase-0 staged loads (they ARE the readiness poll)
        u64 va0, va1, va2, va3;
        va0 = __hip_atomic_load((const u64*)(sbase + 0),  __ATOMIC_RELAXED, __HIP_MEMORY_SCOPE_AGENT);
        va1 = __hip_atomic_load((const u64*)(sbase + 4),  __ATOMIC_RELAXED, __HIP_MEMORY_SCOPE_AGENT);
        va2 = __hip_atomic_load((const u64*)(sbase + 8),  __ATOMIC_RELAXED, __HIP_MEMORY_SCOPE_AGENT);
        va3 = __hip_atomic_load((const u64*)(sbase + 12), __ATOMIC_RELAXED, __HIP_MEMORY_SCOPE_AGENT);

        floatx4 acc_r  = {b_r,  b_r,  b_r,  b_r };
        floatx4 acc_z  = {b_z,  b_z,  b_z,  b_z };
        floatx4 acc_in = {b_in, b_in, b_in, b_in};
        floatx4 acc_hn = {b_hn, b_hn, b_hn, b_hn};

        // gi = x_t @ Wih^T (hides the phase-0 load flight)
        {
            half8 p0 = *(const half8*)(&Wsh[((w << 4) + m16) * 72        + (quad << 3)]);
            half8 p1 = *(const half8*)(&Wsh[(64 + (w << 4) + m16) * 72   + (quad << 3)]);
            half8 p2 = *(const half8*)(&Wsh[(128 + (w << 4) + m16) * 72  + (quad << 3)]);
            acc_r  = __builtin_amdgcn_mfma_f32_16x16x32_f16(ax0, p0, acc_r,  0, 0, 0);
            acc_z  = __builtin_amdgcn_mfma_f32_16x16x32_f16(ax0, p1, acc_z,  0, 0, 0);
            acc_in = __builtin_amdgcn_mfma_f32_16x16x32_f16(ax0, p2, acc_in, 0, 0, 0);
            half8 q0 = *(const half8*)(&Wsh[((w << 4) + m16) * 72        + 32 + (quad << 3)]);
            half8 q1 = *(const half8*)(&Wsh[(64 + (w << 4) + m16) * 72   + 32 + (quad << 3)]);
            half8 q2 = *(const half8*)(&Wsh[(128 + (w << 4) + m16) * 72  + 32 + (quad << 3)]);
            acc_r  = __builtin_amdgcn_mfma_f32_16x16x32_f16(ax1, q0, acc_r,  0, 0, 0);
            acc_z  = __builtin_amdgcn_mfma_f32_16x16x32_f16(ax1, q1, acc_z,  0, 0, 0);
            acc_in = __builtin_amdgcn_mfma_f32_16x16x32_f16(ax1, q2, acc_in, 0, 0, 0);
        }

        // 4 phases: verify staged (sentinel) -> write -> barrier ->
        //           issue next phase -> MFMA this phase
        #pragma unroll
        for (int g = 0; g < 4; ++g) {
            // lazy sentinel verify of this phase's loads (retry only if unready)
            for (;;) {
                bool miss = (va0 == SENT) | (va1 == SENT) | (va2 == SENT) | (va3 == SENT);
                if (!__any(miss)) break;
                __builtin_amdgcn_s_sleep(1);
                const _Float16* sp = sbase + (g << 8);
                if (va0 == SENT) va0 = __hip_atomic_load((const u64*)(sp + 0),  __ATOMIC_RELAXED, __HIP_MEMORY_SCOPE_AGENT);
                if (va1 == SENT) va1 = __hip_atomic_load((const u64*)(sp + 4),  __ATOMIC_RELAXED, __HIP_MEMORY_SCOPE_AGENT);
                if (va2 == SENT) va2 = __hip_atomic_load((const u64*)(sp + 8),  __ATOMIC_RELAXED, __HIP_MEMORY_SCOPE_AGENT);
                if (va3 == SENT) va3 = __hip_atomic_load((const u64*)(sp + 12), __ATOMIC_RELAXED, __HIP_MEMORY_SCOPE_AGENT);
            }
            {
                _Float16* d = &Ash[t & 1][srow * 1032 + (g << 8) + (sch << 4)];
                *(u64*)(d + 0)  = va0;
                *(u64*)(d + 4)  = va1;
                *(u64*)(d + 8)  = va2;
                *(u64*)(d + 12) = va3;
            }
            __syncthreads();
            if (g < 3) {
                // fire next phase's loads (flight hidden under this phase's MFMA)
                const _Float16* sn = sbase + ((g + 1) << 8);
                va0 = __hip_atomic_load((const u64*)(sn + 0),  __ATOMIC_RELAXED, __HIP_MEMORY_SCOPE_AGENT);
                va1 = __hip_atomic_load((const u64*)(sn + 4),  __ATOMIC_RELAXED, __HIP_MEMORY_SCOPE_AGENT);
                va2 = __hip_atomic_load((const u64*)(sn + 8),  __ATOMIC_RELAXED, __HIP_MEMORY_SCOPE_AGENT);
                va3 = __hip_atomic_load((const u64*)(sn + 12), __ATOMIC_RELAXED, __HIP_MEMORY_SCOPE_AGENT);
                #pragma unroll
                for (int j = 0; j < 8; ++j)
                    bnB[j] = *(const half8*)(bnp + ((((g + 1) << 3) + j) << 5));
            }
            #pragma unroll
            for (int j = 0; j < 8; ++j) {
                const int c = (g << 3) + j;
                half8 a = *(const half8*)(&Ash[t & 1][m16 * 1032 + (c << 5) + (quad << 3)]);
                acc_r  = __builtin_amdgcn_mfma_f32_16x16x32_f16(a, br[c], acc_r,  0, 0, 0);
                acc_z  = __builtin_amdgcn_mfma_f32_16x16x32_f16(a, bz[c], acc_z,  0, 0, 0);
                acc_hn = __builtin_amdgcn_mfma_f32_16x16x32_f16(a, bnA[j], acc_hn, 0, 0, 0);
            }
            if (g < 3) {
                #pragma unroll
                for (int j = 0; j < 8; ++j) bnA[j] = bnB[j];
            }
        }

        // epilogue (fire-and-forget publish: no drain, no flag, no end barrier)
        float pv[4];
        #pragma unroll
        for (int i = 0; i < 4; ++i) {
            float rg = fast_sigmoid(acc_r[i]);
            float zg = fast_sigmoid(acc_z[i]);
            float ng = fast_tanh(acc_in[i] + rg * acc_hn[i]);
            float hn2 = (1.f - zg) * ng + zg * hreg[i];
            hreg[i] = hn2;
            pv[i] = hn2 * wo_u;
            Hsh[(w << 8) + ((quad << 2) + i) * 16 + m16] = (_Float16)hn2;
        }
        __threadfence_block();   // order f16 Hsh writes before the u64 read
        {
            u64 hv = *(const u64*)(&Hsh[(w << 8) + prow * 16 + (pc4 << 2)]);
            __hip_atomic_store(
                (u64*)(hdst + ((size_t)(pi16 + prow) << 10) + (qi << 6) + (w << 4) + (pc4 << 2)),
                hv, __ATOMIC_RELAXED, __HIP_MEMORY_SCOPE_AGENT);
        }
        #pragma unroll
        for (int m = 1; m < 16; m <<= 1) {
            #pragma unroll
            for (int i = 0; i < 4; ++i) pv[i] += __shfl_xor(pv[i], m);
        }
        if (m16 == 0) {
            #pragma unroll
            for (int i = 0; i < 4; ++i)
                partials[((size_t)(t << 6) + (qi << 2) + w) * 256 + pi16 + (quad << 2) + i] = pv[i];
        }
    }
}

// ---------------- fallback: verified R13 flag-based GRU (698us) ------------
__global__ __launch_bounds__(256, 1) void gru_flags(
    _Float16* __restrict__ hbuf,
    const float* __restrict__ hprev32, const _Float16* __restrict__ whh16,
    const _Float16* __restrict__ wih16, const _Float16* __restrict__ x16,
    const float* __restrict__ bih, const float* __restrict__ bhh,
    const float* __restrict__ Wo, float* __restrict__ partials,
    unsigned* __restrict__ bar)
{
    __shared__ __align__(16) _Float16 Ash[16 * 1032];
    __shared__ __align__(16) _Float16 Wsh[192 * 72];
    __shared__ __align__(16) _Float16 Hsh[4 * 256];

    const int tid  = threadIdx.x;
    const int w    = tid >> 6;
    const int lane = tid & 63;
    const int m16  = lane & 15;
    const int quad = lane >> 4;
    const int pi   = blockIdx.x & 15;
    const int qi   = blockIdx.x >> 4;
    const int pi16 = pi << 4;
    const int u    = (qi << 6) + (w << 4) + m16;

    for (int idx = tid; idx < 1536; idx += 256) {
        int rowl = idx >> 3, ch = idx & 7;
        int g = rowl >> 6, ru = rowl & 63;
        *(uint4*)(&Wsh[rowl * 72 + (ch << 3)]) =
            *(const uint4*)(wih16 + (size_t)(((g << 10) + (qi << 6) + ru) << 6) + (ch << 3));
    }

    half8 br[32], bz[32];
    {
        const _Float16* p0 = whh16 + ((size_t)u << 10) + (quad << 3);
        const _Float16* p1 = whh16 + ((size_t)(H_ + u) << 10) + (quad << 3);
        #pragma unroll
        for (int c = 0; c < 32; ++c) br[c] = *(const half8*)(p0 + (c << 5));
        #pragma unroll
        for (int c = 0; c < 32; ++c) bz[c] = *(const half8*)(p1 + (c << 5));
    }
    const _Float16* bnp = whh16 + ((size_t)(2 * H_ + u) << 10) + (quad << 3);

    const float b_r  = bih[u]          + bhh[u];
    const float b_z  = bih[H_ + u]     + bhh[H_ + u];
    const float b_in = bih[2 * H_ + u];
    const float b_hn = bhh[2 * H_ + u];
    const float wo_u = Wo[u];

    float hreg[4];
    #pragma unroll
    for (int i = 0; i < 4; ++i)
        hreg[i] = hprev32[((size_t)(pi16 + (quad << 2) + i) << 10) + u];

    __syncthreads();

    unsigned* flag_self       = bar + (((pi << 4) | qi) << 4);
    const unsigned* flag_peer = bar + (((pi << 4) | (lane & 15)) << 4);
    const int srow = tid >> 4;
    const int sch  = tid & 15;
    const int prow = lane >> 2;
    const int pc4  = lane & 3;

    for (int t = 0; t < T_; ++t) {
        const _Float16* hsrc = hbuf + (size_t)(t & 3) * (B_ * H_);
        _Float16*       hdst = hbuf + (size_t)((t + 1) & 3) * (B_ * H_);

        half8 ax0 = *(const half8*)(x16 + (((size_t)t << 8) + pi16 + m16) * WS_ + (quad << 3));
        half8 ax1 = *(const half8*)(x16 + (((size_t)t << 8) + pi16 + m16) * WS_ + 32 + (quad << 3));
        half8 bnA[8], bnB[8];
        #pragma unroll
        for (int j = 0; j < 8; ++j) bnA[j] = *(const half8*)(bnp + (j << 5));

        const unsigned need = (unsigned)t;
        u64 rdy = 0;

        while ((rdy & 0xFull) != 0xFull) {
            unsigned f = 0;
            if (lane < 16)
                f = __hip_atomic_load(flag_peer, __ATOMIC_RELAXED, __HIP_MEMORY_SCOPE_AGENT);
            rdy |= __ballot(f >= need);
            if ((rdy & 0xFull) != 0xFull) __builtin_amdgcn_s_sleep(1);
        }
        u64 va0, va1, va2, va3;
        {
            const _Float16* s = hsrc + ((size_t)(pi16 + srow) << 10) + (sch << 4);
            va0 = __hip_atomic_load((const u64*)(s + 0),  __ATOMIC_RELAXED, __HIP_MEMORY_SCOPE_AGENT);
            va1 = __hip_atomic_load((const u64*)(s + 4),  __ATOMIC_RELAXED, __HIP_MEMORY_SCOPE_AGENT);
            va2 = __hip_atomic_load((const u64*)(s + 8),  __ATOMIC_RELAXED, __HIP_MEMORY_SCOPE_AGENT);
            va3 = __hip_atomic_load((const u64*)(s + 12), __ATOMIC_RELAXED, __HIP_MEMORY_SCOPE_AGENT);
        }

        floatx4 acc_r  = {b_r,  b_r,  b_r,  b_r };
        floatx4 acc_z  = {b_z,  b_z,  b_z,  b_z };
        floatx4 acc_in = {b_in, b_in, b_in, b_in};
        floatx4 acc_hn = {b_hn, b_hn, b_hn, b_hn};

        {
            half8 p0 = *(const half8*)(&Wsh[((w << 4) + m16) * 72        + (quad << 3)]);
            half8 p1 = *(const half8*)(&Wsh[(64 + (w << 4) + m16) * 72   + (quad << 3)]);
            half8 p2 = *(const half8*)(&Wsh[(128 + (w << 4) + m16) * 72  + (quad << 3)]);
            acc_r  = __builtin_amdgcn_mfma_f32_16x16x32_f16(ax0, p0, acc_r,  0, 0, 0);
            acc_z  = __builtin_amdgcn_mfma_f32_16x16x32_f16(ax0, p1, acc_z,  0, 0, 0);
            acc_in = __builtin_amdgcn_mfma_f32_16x16x32_f16(ax0, p2, acc_in, 0, 0, 0);
            half8 q0 = *(const half8*)(&Wsh[((w << 4) + m16) * 72        + 32 + (quad << 3)]);
            half8 q1 = *(const half8*)(&Wsh[(64 + (w << 4) + m16) * 72   + 32 + (quad << 3)]);
            half8 q2 = *(const half8*)(&Wsh[(128 + (w << 4) + m16) * 72  + 32 + (quad << 3)]);
            acc_r  = __builtin_amdgcn_mfma_f32_16x16x32_f16(ax1, q0, acc_r,  0, 0, 0);
            acc_z  = __builtin_amdgcn_mfma_f32_16x16x32_f16(ax1, q1, acc_z,  0, 0, 0);
            acc_in = __builtin_amdgcn_mfma_f32_16x16x32_f16(ax1, q2, acc_in, 0, 0, 0);
        }

        #pragma unroll
        for (int g = 0; g < 4; ++g) {
            {
                _Float16* d = &Ash[srow * 1032 + (g << 8) + (sch << 4)];
                *(u64*)(d + 0)  = va0;
                *(u64*)(d + 4)  = va1;
                *(u64*)(d + 8)  = va2;
                *(u64*)(d + 12) = va3;
            }
            __syncthreads();
            if (g < 3) {
                const u64 mask = 0xFull << ((g + 1) << 2);
                while ((rdy & mask) != mask) {
                    unsigned f = 0;
                    if (lane < 16)
                        f = __hip_atomic_load(flag_peer, __ATOMIC_RELAXED, __HIP_MEMORY_SCOPE_AGENT);
                    rdy |= __ballot(f >= need);
                    if ((rdy & mask) != mask) __builtin_amdgcn_s_sleep(1);
                }
                const _Float16* s = hsrc + ((size_t)(pi16 + srow) << 10) + ((g + 1) << 8) + (sch << 4);
                va0 = __hip_atomic_load((const u64*)(s + 0),  __ATOMIC_RELAXED, __HIP_MEMORY_SCOPE_AGENT);
                va1 = __hip_atomic_load((const u64*)(s + 4),  __ATOMIC_RELAXED, __HIP_MEMORY_SCOPE_AGENT);
                va2 = __hip_atomic_load((const u64*)(s + 8),  __ATOMIC_RELAXED, __HIP_MEMORY_SCOPE_AGENT);
                va3 = __hip_atomic_load((const u64*)(s + 12), __ATOMIC_RELAXED, __HIP_MEMORY_SCOPE_AGENT);
                #pragma unroll
                for (int j = 0; j < 8; ++j)
                    bnB[j] = *(const half8*)(bnp + ((((g + 1) << 3) + j) << 5));
            }
            #pragma unroll
            for (int j = 0; j < 8; ++j) {
                const int c = (g << 3) + j;
                half8 a = *(const half8*)(&Ash[m16 * 1032 + (c << 5) + (quad << 3)]);
                acc_r  = __builtin_amdgcn_mfma_f32_16x16x32_f16(a, br[c], acc_r,  0, 0, 0);
                acc_z  = __builtin_amdgcn_mfma_f32_16x16x32_f16(a, bz[c], acc_z,  0, 0, 0);
                acc_hn = __builtin_amdgcn_mfma_f32_16x16x32_f16(a, bnA[j], acc_hn, 0, 0, 0);
            }
            if (g < 3) {
                #pragma unroll
                for (int j = 0; j < 8; ++j) bnA[j] = bnB[j];
            }
        }

        float pv[4];
        #pragma unroll
        for (int i = 0; i < 4; ++i) {
            float rg = fast_sigmoid(acc_r[i]);
            float zg = fast_sigmoid(acc_z[i]);
            float ng = fast_tanh(acc_in[i] + rg * acc_hn[i]);
            float hn2 = (1.f - zg) * ng + zg * hreg[i];
            hreg[i] = hn2;
            pv[i] = hn2 * wo_u;
            Hsh[(w << 8) + ((quad << 2) + i) * 16 + m16] = (_Float16)hn2;
        }
        __threadfence_block();
        {
            u64 hv = *(const u64*)(&Hsh[(w << 8) + prow * 16 + (pc4 << 2)]);
            __hip_atomic_store(
                (u64*)(hdst + ((size_t)(pi16 + prow) << 10) + (qi << 6) + (w << 4) + (pc4 << 2)),
                hv, __ATOMIC_RELAXED, __HIP_MEMORY_SCOPE_AGENT);
        }
        #pragma unroll
        for (int m = 1; m < 16; m <<= 1) {
            #pragma unroll
            for (int i = 0; i < 4; ++i) pv[i] += __shfl_xor(pv[i], m);
        }
        asm volatile("s_waitcnt vmcnt(0)" ::: "memory");
        __syncthreads();
        if (tid == 0)
            __hip_atomic_store(flag_self, (unsigned)(t + 1),
                               __ATOMIC_RELAXED, __HIP_MEMORY_SCOPE_AGENT);
        if (m16 == 0) {
            #pragma unroll
            for (int i = 0; i < 4; ++i)
                partials[((size_t)(t << 6) + (qi << 2) + w) * 256 + pi16 + (quad << 2) + i] = pv[i];
        }
    }
}

// ---------------- final reduce (coalesced over transposed partials) --------
__global__ void out_reduce(const float* __restrict__ partials, const float* __restrict__ bo,
                           float* __restrict__ out) {
    int t = blockIdx.x, r = threadIdx.x;
    float s = 0.f;
    #pragma unroll
    for (int k = 0; k < 64; ++k) s += partials[((size_t)(t << 6) + k) * 256 + r];
    out[(size_t)r * T_ + t] = s + bo[0];
}

extern "C" void kernel_launch(void* const* d_in, const int* in_sizes, int n_in,
                              void* d_out, int out_size, void* d_ws, size_t ws_size,
                              hipStream_t stream) {
    const float* lag  = (const float*)d_in[0];
    const float* curr = (const float*)d_in[1];
    const float* W1   = (const float*)d_in[2];
    const float* b1   = (const float*)d_in[3];
    const float* W2   = (const float*)d_in[4];
    const float* b2   = (const float*)d_in[5];
    const float* W3   = (const float*)d_in[6];
    const float* b3   = (const float*)d_in[7];
    const float* Wih  = (const float*)d_in[8];
    const float* Whh  = (const float*)d_in[9];
    const float* bih  = (const float*)d_in[10];
    const float* bhh  = (const float*)d_in[11];
    const float* Wo   = (const float*)d_in[12];
    const float* bo   = (const float*)d_in[13];
    float* out = (float*)d_out;

    char* ws = (char*)d_ws;
    size_t off = 0;
    auto alloc = [&](size_t bytes) -> void* {
        void* p = ws + off;
        off += (bytes + 255) & ~(size_t)255;
        return p;
    };
    _Float16* whh16 = (_Float16*)alloc((size_t)3 * H_ * H_ * 2);
    _Float16* wih16 = (_Float16*)alloc((size_t)3 * H_ * WS_ * 2);
    _Float16* x16   = (_Float16*)alloc((size_t)T_ * B_ * WS_ * 2);
    float* hprev32  = (float*)alloc((size_t)B_ * H_ * 4);
    float* partials = (float*)alloc((size_t)T_ * B_ * 64 * 4);
    unsigned* bar   = (unsigned*)alloc(81920);

    const size_t slot_bytes = (size_t)B_ * H_ * 2;
    const size_t ring_bytes = (size_t)(T_ + 1) * slot_bytes;   // 169 slots, ~88.6 MB
    const bool sentinel_mode = (ws_size >= off + ring_bytes + 4096);
    _Float16* hring = (_Float16*)alloc(sentinel_mode ? ring_bytes : 4 * slot_bytes);

    if (sentinel_mode) {
        // poison slots 1..168 (slot 0 is fully written by enc_fused)
        hipMemsetAsync((char*)hring + slot_bytes, 0xFF, ring_bytes - slot_bytes, stream);
    } else {
        hipMemsetAsync(bar, 0, 81920, stream);
    }

    const int na = 3 * H_ * H_ / 4;
    const int nb = 3 * H_ * WS_ / 4;
    const int nc = T_ * B_ * WS_ / 4;
    const int ntot = na + nb + nc;
    cvt_all<<<(ntot + 255) / 256, 256, 0, stream>>>(
        (const float4*)Whh, (half4*)whh16, na,
        (const float4*)Wih, (half4*)wih16, nb,
        (const float4*)curr, (half4*)x16, nc);

    enc_fused<<<B_, 256, 0, stream>>>(lag, W1, b1, W2, b2, W3, b3, hprev32, hring);

    if (sentinel_mode)
        gru_sentinel<<<dim3(256), dim3(256), 0, stream>>>(
            hring, hprev32, whh16, wih16, x16, bih, bhh, Wo, partials);
    else
        gru_flags<<<dim3(256), dim3(256), 0, stream>>>(
            hring, hprev32, whh16, wih16, x16, bih, bhh, Wo, partials, bar);

    out_reduce<<<T_, B_, 0, stream>>>(partials, bo, out);
}

// Round 8
// 813.535 us; speedup vs baseline: 1.4531x; 1.4531x over previous
//
#include <hip/hip_runtime.h>
#include <hip/hip_bf16.h>
#include <cstdint>
#include <cstddef>

typedef _Float16 half8 __attribute__((ext_vector_type(8)));
typedef _Float16 half4 __attribute__((ext_vector_type(4)));
typedef float floatx4 __attribute__((ext_vector_type(4)));
typedef unsigned long long u64;

#define B_ 256
#define T_ 168
#define H_ 1024
#define WS_ 64
#define LAG_ 168
#define LAT_ 128
#define SENT 0xFFFFFFFFFFFFFFFFull

__device__ __forceinline__ float fast_sigmoid(float x) {
    return __builtin_amdgcn_rcpf(1.f + __expf(-x));
}
__device__ __forceinline__ float fast_tanh(float x) {
    return 1.f - 2.f * __builtin_amdgcn_rcpf(__expf(2.f * x) + 1.f);
}

// ---------------- fp32 -> fp16 conversion (merged: 3 buffers, 1 launch) ----
__global__ void cvt_all(const float4* __restrict__ a, half4* __restrict__ da, int na,
                        const float4* __restrict__ b, half4* __restrict__ db, int nb,
                        const float4* __restrict__ c, half4* __restrict__ dc, int nc) {
    int i = blockIdx.x * blockDim.x + threadIdx.x;
    const float4* s;
    half4* d;
    int j = i;
    if (j < na) { s = a; d = da; }
    else {
        j -= na;
        if (j < nb) { s = b; d = db; }
        else {
            j -= nb;
            if (j >= nc) return;
            s = c; d = dc;
        }
    }
    float4 v = s[j];
    half4 o;
    o[0] = (_Float16)v.x; o[1] = (_Float16)v.y;
    o[2] = (_Float16)v.z; o[3] = (_Float16)v.w;
    d[j] = o;
}

// ---------------- fused encoder: lag -> 64 -> 128 -> 1024 (one kernel) -----
__global__ void enc_fused(const float* __restrict__ lag,
                          const float* __restrict__ W1, const float* __restrict__ b1,
                          const float* __restrict__ W2, const float* __restrict__ b2,
                          const float* __restrict__ W3, const float* __restrict__ b3,
                          float* __restrict__ hprev32, _Float16* __restrict__ h0f16) {
    __shared__ float lrow[LAG_];
    __shared__ float l1[64];
    __shared__ float l2[LAT_];
    const int r = blockIdx.x, tid = threadIdx.x;
    if (tid < LAG_) lrow[tid] = lag[(size_t)r * LAG_ + tid];
    __syncthreads();
    if (tid < 64) {
        const float* w = W1 + (size_t)tid * LAG_;
        float s = b1[tid];
        for (int k = 0; k < LAG_; ++k) s += lrow[k] * w[k];
        l1[tid] = (s >= 0.f) ? s : 0.01f * s;
    }
    __syncthreads();
    if (tid < LAT_) {
        const float* w = W2 + (size_t)tid * 64;
        float s = b2[tid];
        for (int k = 0; k < 64; ++k) s += l1[k] * w[k];
        l2[tid] = (s >= 0.f) ? s : 0.01f * s;
    }
    __syncthreads();
    for (int j = tid; j < H_; j += 256) {
        const float* w = W3 + (size_t)j * LAT_;
        float acc = b3[j];
        #pragma unroll 8
        for (int k = 0; k < LAT_; ++k) acc += l2[k] * w[k];
        hprev32[(size_t)r * H_ + j] = acc;
        h0f16[(size_t)r * H_ + j]   = (_Float16)acc;
    }
}

// ---------------- R17: hybrid GRU — R13 flag loop + speculative prefetch ----
// Lessons R13-R16: flag polling (16 light lane-loads) is cheap; sentinel
// RE-POLLING of data (1024 loads/block/retry) inflates MALL RTT massively
// (R15 865us, R16 1111us). The removable cost is the per-phase DATA-LOAD RTT,
// not the signaling. Ring (169 slots) is WRITE-ONCE: poison 0xFF..F -> final
// value, one aligned 8B store per u64 (single-copy atomic). Therefore a
// prefetched u64 != SENT is guaranteed final WITHOUT any flag. Scheme:
//   - one-shot burst prefetch of all 16 staged u64s at step start (under gi),
//   - per phase: if wave's 4 values non-SENT -> skip flag wait, use them;
//     else R13's light flag wait (producer drain+flag kept verbatim, so
//     flag => data visible) + single reload (guaranteed hit). No retry storm.
// Worst case == R13; steady-state lockstep -> zero consumer-side RTT.
// R9 fix retained: __threadfence_block between Hsh f16 writes / u64 read.
__global__ __launch_bounds__(256, 1) void gru_hybrid(
    _Float16* __restrict__ hring,
    const float* __restrict__ hprev32, const _Float16* __restrict__ whh16,
    const _Float16* __restrict__ wih16, const _Float16* __restrict__ x16,
    const float* __restrict__ bih, const float* __restrict__ bhh,
    const float* __restrict__ Wo, float* __restrict__ partials,
    unsigned* __restrict__ bar)
{
    __shared__ __align__(16) _Float16 Ash[16 * 1032];
    __shared__ __align__(16) _Float16 Wsh[192 * 72];
    __shared__ __align__(16) _Float16 Hsh[4 * 256];

    const int tid  = threadIdx.x;
    const int w    = tid >> 6;
    const int lane = tid & 63;
    const int m16  = lane & 15;
    const int quad = lane >> 4;
    const int pi   = blockIdx.x & 15;
    const int qi   = blockIdx.x >> 4;
    const int pi16 = pi << 4;
    const int u    = (qi << 6) + (w << 4) + m16;

    // Wih slice -> LDS (once)
    for (int idx = tid; idx < 1536; idx += 256) {
        int rowl = idx >> 3, ch = idx & 7;
        int g = rowl >> 6, ru = rowl & 63;
        *(uint4*)(&Wsh[rowl * 72 + (ch << 3)]) =
            *(const uint4*)(wih16 + (size_t)(((g << 10) + (qi << 6) + ru) << 6) + (ch << 3));
    }

    // Resident Whh: r,z gates (AGPR-backed); n streamed per phase
    half8 br[32], bz[32];
    {
        const _Float16* p0 = whh16 + ((size_t)u << 10) + (quad << 3);
        const _Float16* p1 = whh16 + ((size_t)(H_ + u) << 10) + (quad << 3);
        #pragma unroll
        for (int c = 0; c < 32; ++c) br[c] = *(const half8*)(p0 + (c << 5));
        #pragma unroll
        for (int c = 0; c < 32; ++c) bz[c] = *(const half8*)(p1 + (c << 5));
    }
    const _Float16* bnp = whh16 + ((size_t)(2 * H_ + u) << 10) + (quad << 3);

    const float b_r  = bih[u]          + bhh[u];
    const float b_z  = bih[H_ + u]     + bhh[H_ + u];
    const float b_in = bih[2 * H_ + u];
    const float b_hn = bhh[2 * H_ + u];
    const float wo_u = Wo[u];

    float hreg[4];
    #pragma unroll
    for (int i = 0; i < 4; ++i)
        hreg[i] = hprev32[((size_t)(pi16 + (quad << 2) + i) << 10) + u];

    __syncthreads();

    unsigned* flag_self       = bar + (((pi << 4) | qi) << 4);
    const unsigned* flag_peer = bar + (((pi << 4) | (lane & 15)) << 4); // lanes 0..15
    const int srow = tid >> 4;
    const int sch  = tid & 15;
    const int prow = lane >> 2;
    const int pc4  = lane & 3;

    for (int t = 0; t < T_; ++t) {
        const _Float16* hsrc = hring + (size_t)t * (B_ * H_);
        _Float16*       hdst = hring + (size_t)(t + 1) * (B_ * H_);

        // h-independent prefetch
        half8 ax0 = *(const half8*)(x16 + (((size_t)t << 8) + pi16 + m16) * WS_ + (quad << 3));
        half8 ax1 = *(const half8*)(x16 + (((size_t)t << 8) + pi16 + m16) * WS_ + 32 + (quad << 3));
        half8 bnA[8], bnB[8];
        #pragma unroll
        for (int j = 0; j < 8; ++j) bnA[j] = *(const half8*)(bnp + (j << 5));

        const _Float16* sbase = hsrc + ((size_t)(pi16 + srow) << 10) + (sch << 4);

        // one-shot speculative burst prefetch of ALL 4 phases (write-once ring:
        // any non-SENT value is final)
        u64 pf0a, pf0b, pf0c, pf0d, pf1a, pf1b, pf1c, pf1d;
        u64 pf2a, pf2b, pf2c, pf2d, pf3a, pf3b, pf3c, pf3d;
        pf0a = __hip_atomic_load((const u64*)(sbase + 0),        __ATOMIC_RELAXED, __HIP_MEMORY_SCOPE_AGENT);
        pf0b = __hip_atomic_load((const u64*)(sbase + 4),        __ATOMIC_RELAXED, __HIP_MEMORY_SCOPE_AGENT);
        pf0c = __hip_atomic_load((const u64*)(sbase + 8),        __ATOMIC_RELAXED, __HIP_MEMORY_SCOPE_AGENT);
        pf0d = __hip_atomic_load((const u64*)(sbase + 12),       __ATOMIC_RELAXED, __HIP_MEMORY_SCOPE_AGENT);
        pf1a = __hip_atomic_load((const u64*)(sbase + 256 + 0),  __ATOMIC_RELAXED, __HIP_MEMORY_SCOPE_AGENT);
        pf1b = __hip_atomic_load((const u64*)(sbase + 256 + 4),  __ATOMIC_RELAXED, __HIP_MEMORY_SCOPE_AGENT);
        pf1c = __hip_atomic_load((const u64*)(sbase + 256 + 8),  __ATOMIC_RELAXED, __HIP_MEMORY_SCOPE_AGENT);
        pf1d = __hip_atomic_load((const u64*)(sbase + 256 + 12), __ATOMIC_RELAXED, __HIP_MEMORY_SCOPE_AGENT);
        pf2a = __hip_atomic_load((const u64*)(sbase + 512 + 0),  __ATOMIC_RELAXED, __HIP_MEMORY_SCOPE_AGENT);
        pf2b = __hip_atomic_load((const u64*)(sbase + 512 + 4),  __ATOMIC_RELAXED, __HIP_MEMORY_SCOPE_AGENT);
        pf2c = __hip_atomic_load((const u64*)(sbase + 512 + 8),  __ATOMIC_RELAXED, __HIP_MEMORY_SCOPE_AGENT);
        pf2d = __hip_atomic_load((const u64*)(sbase + 512 + 12), __ATOMIC_RELAXED, __HIP_MEMORY_SCOPE_AGENT);
        pf3a = __hip_atomic_load((const u64*)(sbase + 768 + 0),  __ATOMIC_RELAXED, __HIP_MEMORY_SCOPE_AGENT);
        pf3b = __hip_atomic_load((const u64*)(sbase + 768 + 4),  __ATOMIC_RELAXED, __HIP_MEMORY_SCOPE_AGENT);
        pf3c = __hip_atomic_load((const u64*)(sbase + 768 + 8),  __ATOMIC_RELAXED, __HIP_MEMORY_SCOPE_AGENT);
        pf3d = __hip_atomic_load((const u64*)(sbase + 768 + 12), __ATOMIC_RELAXED, __HIP_MEMORY_SCOPE_AGENT);

        floatx4 acc_r  = {b_r,  b_r,  b_r,  b_r };
        floatx4 acc_z  = {b_z,  b_z,  b_z,  b_z };
        floatx4 acc_in = {b_in, b_in, b_in, b_in};
        floatx4 acc_hn = {b_hn, b_hn, b_hn, b_hn};

        // gi = x_t @ Wih^T (hides the prefetch flight)
        {
            half8 p0 = *(const half8*)(&Wsh[((w << 4) + m16) * 72        + (quad << 3)]);
            half8 p1 = *(const half8*)(&Wsh[(64 + (w << 4) + m16) * 72   + (quad << 3)]);
            half8 p2 = *(const half8*)(&Wsh[(128 + (w << 4) + m16) * 72  + (quad << 3)]);
            acc_r  = __builtin_amdgcn_mfma_f32_16x16x32_f16(ax0, p0, acc_r,  0, 0, 0);
            acc_z  = __builtin_amdgcn_mfma_f32_16x16x32_f16(ax0, p1, acc_z,  0, 0, 0);
            acc_in = __builtin_amdgcn_mfma_f32_16x16x32_f16(ax0, p2, acc_in, 0, 0, 0);
            half8 q0 = *(const half8*)(&Wsh[((w << 4) + m16) * 72        + 32 + (quad << 3)]);
            half8 q1 = *(const half8*)(&Wsh[(64 + (w << 4) + m16) * 72   + 32 + (quad << 3)]);
            half8 q2 = *(const half8*)(&Wsh[(128 + (w << 4) + m16) * 72  + 32 + (quad << 3)]);
            acc_r  = __builtin_amdgcn_mfma_f32_16x16x32_f16(ax1, q0, acc_r,  0, 0, 0);
            acc_z  = __builtin_amdgcn_mfma_f32_16x16x32_f16(ax1, q1, acc_z,  0, 0, 0);
            acc_in = __builtin_amdgcn_mfma_f32_16x16x32_f16(ax1, q2, acc_in, 0, 0, 0);
        }

        const unsigned need = (unsigned)t;
        u64 rdy = 0;
        u64 va0, va1, va2, va3;

        // resolve phase g: use prefetched values if complete, else light flag
        // wait (R13) + single guaranteed-hit reload of the missing u64s.
        #define RESOLVE_PHASE(G, A, Bv, C, D)                                            \
        {                                                                                \
            bool miss = (A == SENT) | (Bv == SENT) | (C == SENT) | (D == SENT);          \
            if (__any(miss)) {                                                           \
                const u64 mask = 0xFull << ((G) << 2);                                   \
                while ((rdy & mask) != mask) {                                           \
                    unsigned f = 0;                                                      \
                    if (lane < 16)                                                       \
                        f = __hip_atomic_load(flag_peer, __ATOMIC_RELAXED,               \
                                              __HIP_MEMORY_SCOPE_AGENT);                 \
                    rdy |= __ballot(f >= need);                                          \
                    if ((rdy & mask) != mask) __builtin_amdgcn_s_sleep(1);               \
                }                                                                        \
                const _Float16* sp = sbase + ((G) << 8);                                 \
                if (A  == SENT) A  = __hip_atomic_load((const u64*)(sp + 0),             \
                                        __ATOMIC_RELAXED, __HIP_MEMORY_SCOPE_AGENT);     \
                if (Bv == SENT) Bv = __hip_atomic_load((const u64*)(sp + 4),             \
                                        __ATOMIC_RELAXED, __HIP_MEMORY_SCOPE_AGENT);     \
                if (C  == SENT) C  = __hip_atomic_load((const u64*)(sp + 8),             \
                                        __ATOMIC_RELAXED, __HIP_MEMORY_SCOPE_AGENT);     \
                if (D  == SENT) D  = __hip_atomic_load((const u64*)(sp + 12),            \
                                        __ATOMIC_RELAXED, __HIP_MEMORY_SCOPE_AGENT);     \
            }                                                                            \
            va0 = A; va1 = Bv; va2 = C; va3 = D;                                         \
        }

        RESOLVE_PHASE(0, pf0a, pf0b, pf0c, pf0d)

        #pragma unroll
        for (int g = 0; g < 4; ++g) {
            {
                _Float16* d = &Ash[srow * 1032 + (g << 8) + (sch << 4)];
                *(u64*)(d + 0)  = va0;
                *(u64*)(d + 4)  = va1;
                *(u64*)(d + 8)  = va2;
                *(u64*)(d + 12) = va3;
            }
            __syncthreads();
            if (g == 0) RESOLVE_PHASE(1, pf1a, pf1b, pf1c, pf1d)
            else if (g == 1) RESOLVE_PHASE(2, pf2a, pf2b, pf2c, pf2d)
            else if (g == 2) RESOLVE_PHASE(3, pf3a, pf3b, pf3c, pf3d)
            if (g < 3) {
                #pragma unroll
                for (int j = 0; j < 8; ++j)
                    bnB[j] = *(const half8*)(bnp + ((((g + 1) << 3) + j) << 5));
            }
            #pragma unroll
            for (int j = 0; j < 8; ++j) {
                const int c = (g << 3) + j;
                half8 a = *(const half8*)(&Ash[m16 * 1032 + (c << 5) + (quad << 3)]);
                acc_r  = __builtin_amdgcn_mfma_f32_16x16x32_f16(a, br[c], acc_r,  0, 0, 0);
                acc_z  = __builtin_amdgcn_mfma_f32_16x16x32_f16(a, bz[c], acc_z,  0, 0, 0);
                acc_hn = __builtin_amdgcn_mfma_f32_16x16x32_f16(a, bnA[j], acc_hn, 0, 0, 0);
            }
            if (g < 3) {
                #pragma unroll
                for (int j = 0; j < 8; ++j) bnA[j] = bnB[j];
            }
        }
        #undef RESOLVE_PHASE

        // epilogue: producer drain + flag kept VERBATIM (flag => data visible)
        float pv[4];
        #pragma unroll
        for (int i = 0; i < 4; ++i) {
            float rg = fast_sigmoid(acc_r[i]);
            float zg = fast_sigmoid(acc_z[i]);
            float ng = fast_tanh(acc_in[i] + rg * acc_hn[i]);
            float hn2 = (1.f - zg) * ng + zg * hreg[i];
            hreg[i] = hn2;
            pv[i] = hn2 * wo_u;
            Hsh[(w << 8) + ((quad << 2) + i) * 16 + m16] = (_Float16)hn2;
        }
        __threadfence_block();
        {
            u64 hv = *(const u64*)(&Hsh[(w << 8) + prow * 16 + (pc4 << 2)]);
            __hip_atomic_store(
                (u64*)(hdst + ((size_t)(pi16 + prow) << 10) + (qi << 6) + (w << 4) + (pc4 << 2)),
                hv, __ATOMIC_RELAXED, __HIP_MEMORY_SCOPE_AGENT);
        }
        #pragma unroll
        for (int m = 1; m < 16; m <<= 1) {
            #pragma unroll
            for (int i = 0; i < 4; ++i) pv[i] += __shfl_xor(pv[i], m);
        }
        asm volatile("s_waitcnt vmcnt(0)" ::: "memory");
        __syncthreads();
        if (tid == 0)
            __hip_atomic_store(flag_self, (unsigned)(t + 1),
                               __ATOMIC_RELAXED, __HIP_MEMORY_SCOPE_AGENT);
        if (m16 == 0) {
            #pragma unroll
            for (int i = 0; i < 4; ++i)
                partials[((size_t)(t << 6) + (qi << 2) + w) * 256 + pi16 + (quad << 2) + i] = pv[i];
        }
    }
}

// ---------------- fallback: verified R13 flag-based GRU (698us) ------------
__global__ __launch_bounds__(256, 1) void gru_flags(
    _Float16* __restrict__ hbuf,
    const float* __restrict__ hprev32, const _Float16* __restrict__ whh16,
    const _Float16* __restrict__ wih16, const _Float16* __restrict__ x16,
    const float* __restrict__ bih, const float* __restrict__ bhh,
    const float* __restrict__ Wo, float* __restrict__ partials,
    unsigned* __restrict__ bar)
{
    __shared__ __align__(16) _Float16 Ash[16 * 1032];
    __shared__ __align__(16) _Float16 Wsh[192 * 72];
    __shared__ __align__(16) _Float16 Hsh[4 * 256];

    const int tid  = threadIdx.x;
    const int w    = tid >> 6;
    const int lane = tid & 63;
    const int m16  = lane & 15;
    const int quad = lane >> 4;
    const int pi   = blockIdx.x & 15;
    const int qi   = blockIdx.x >> 4;
    const int pi16 = pi << 4;
    const int u    = (qi << 6) + (w << 4) + m16;

    for (int idx = tid; idx < 1536; idx += 256) {
        int rowl = idx >> 3, ch = idx & 7;
        int g = rowl >> 6, ru = rowl & 63;
        *(uint4*)(&Wsh[rowl * 72 + (ch << 3)]) =
            *(const uint4*)(wih16 + (size_t)(((g << 10) + (qi << 6) + ru) << 6) + (ch << 3));
    }

    half8 br[32], bz[32];
    {
        const _Float16* p0 = whh16 + ((size_t)u << 10) + (quad << 3);
        const _Float16* p1 = whh16 + ((size_t)(H_ + u) << 10) + (quad << 3);
        #pragma unroll
        for (int c = 0; c < 32; ++c) br[c] = *(const half8*)(p0 + (c << 5));
        #pragma unroll
        for (int c = 0; c < 32; ++c) bz[c] = *(const half8*)(p1 + (c << 5));
    }
    const _Float16* bnp = whh16 + ((size_t)(2 * H_ + u) << 10) + (quad << 3);

    const float b_r  = bih[u]          + bhh[u];
    const float b_z  = bih[H_ + u]     + bhh[H_ + u];
    const float b_in = bih[2 * H_ + u];
    const float b_hn = bhh[2 * H_ + u];
    const float wo_u = Wo[u];

    float hreg[4];
    #pragma unroll
    for (int i = 0; i < 4; ++i)
        hreg[i] = hprev32[((size_t)(pi16 + (quad << 2) + i) << 10) + u];

    __syncthreads();

    unsigned* flag_self       = bar + (((pi << 4) | qi) << 4);
    const unsigned* flag_peer = bar + (((pi << 4) | (lane & 15)) << 4);
    const int srow = tid >> 4;
    const int sch  = tid & 15;
    const int prow = lane >> 2;
    const int pc4  = lane & 3;

    for (int t = 0; t < T_; ++t) {
        const _Float16* hsrc = hbuf + (size_t)(t & 3) * (B_ * H_);
        _Float16*       hdst = hbuf + (size_t)((t + 1) & 3) * (B_ * H_);

        half8 ax0 = *(const half8*)(x16 + (((size_t)t << 8) + pi16 + m16) * WS_ + (quad << 3));
        half8 ax1 = *(const half8*)(x16 + (((size_t)t << 8) + pi16 + m16) * WS_ + 32 + (quad << 3));
        half8 bnA[8], bnB[8];
        #pragma unroll
        for (int j = 0; j < 8; ++j) bnA[j] = *(const half8*)(bnp + (j << 5));

        const unsigned need = (unsigned)t;
        u64 rdy = 0;

        while ((rdy & 0xFull) != 0xFull) {
            unsigned f = 0;
            if (lane < 16)
                f = __hip_atomic_load(flag_peer, __ATOMIC_RELAXED, __HIP_MEMORY_SCOPE_AGENT);
            rdy |= __ballot(f >= need);
            if ((rdy & 0xFull) != 0xFull) __builtin_amdgcn_s_sleep(1);
        }
        u64 va0, va1, va2, va3;
        {
            const _Float16* s = hsrc + ((size_t)(pi16 + srow) << 10) + (sch << 4);
            va0 = __hip_atomic_load((const u64*)(s + 0),  __ATOMIC_RELAXED, __HIP_MEMORY_SCOPE_AGENT);
            va1 = __hip_atomic_load((const u64*)(s + 4),  __ATOMIC_RELAXED, __HIP_MEMORY_SCOPE_AGENT);
            va2 = __hip_atomic_load((const u64*)(s + 8),  __ATOMIC_RELAXED, __HIP_MEMORY_SCOPE_AGENT);
            va3 = __hip_atomic_load((const u64*)(s + 12), __ATOMIC_RELAXED, __HIP_MEMORY_SCOPE_AGENT);
        }

        floatx4 acc_r  = {b_r,  b_r,  b_r,  b_r };
        floatx4 acc_z  = {b_z,  b_z,  b_z,  b_z };
        floatx4 acc_in = {b_in, b_in, b_in, b_in};
        floatx4 acc_hn = {b_hn, b_hn, b_hn, b_hn};

        {
            half8 p0 = *(const half8*)(&Wsh[((w << 4) + m16) * 72        + (quad << 3)]);
            half8 p1 = *(const half8*)(&Wsh[(64 + (w << 4) + m16) * 72   + (quad << 3)]);
            half8 p2 = *(const half8*)(&Wsh[(128 + (w << 4) + m16) * 72  + (quad << 3)]);
            acc_r  = __builtin_amdgcn_mfma_f32_16x16x32_f16(ax0, p0, acc_r,  0, 0, 0);
            acc_z  = __builtin_amdgcn_mfma_f32_16x16x32_f16(ax0, p1, acc_z,  0, 0, 0);
            acc_in = __builtin_amdgcn_mfma_f32_16x16x32_f16(ax0, p2, acc_in, 0, 0, 0);
            half8 q0 = *(const half8*)(&Wsh[((w << 4) + m16) * 72        + 32 + (quad << 3)]);
            half8 q1 = *(const half8*)(&Wsh[(64 + (w << 4) + m16) * 72   + 32 + (quad << 3)]);
            half8 q2 = *(const half8*)(&Wsh[(128 + (w << 4) + m16) * 72  + 32 + (quad << 3)]);
            acc_r  = __builtin_amdgcn_mfma_f32_16x16x32_f16(ax1, q0, acc_r,  0, 0, 0);
            acc_z  = __builtin_amdgcn_mfma_f32_16x16x32_f16(ax1, q1, acc_z,  0, 0, 0);
            acc_in = __builtin_amdgcn_mfma_f32_16x16x32_f16(ax1, q2, acc_in, 0, 0, 0);
        }

        #pragma unroll
        for (int g = 0; g < 4; ++g) {
            {
                _Float16* d = &Ash[srow * 1032 + (g << 8) + (sch << 4)];
                *(u64*)(d + 0)  = va0;
                *(u64*)(d + 4)  = va1;
                *(u64*)(d + 8)  = va2;
                *(u64*)(d + 12) = va3;
            }
            __syncthreads();
            if (g < 3) {
                const u64 mask = 0xFull << ((g + 1) << 2);
                while ((rdy & mask) != mask) {
                    unsigned f = 0;
                    if (lane < 16)
                        f = __hip_atomic_load(flag_peer, __ATOMIC_RELAXED, __HIP_MEMORY_SCOPE_AGENT);
                    rdy |= __ballot(f >= need);
                    if ((rdy & mask) != mask) __builtin_amdgcn_s_sleep(1);
                }
                const _Float16* s = hsrc + ((size_t)(pi16 + srow) << 10) + ((g + 1) << 8) + (sch << 4);
                va0 = __hip_atomic_load((const u64*)(s + 0),  __ATOMIC_RELAXED, __HIP_MEMORY_SCOPE_AGENT);
                va1 = __hip_atomic_load((const u64*)(s + 4),  __ATOMIC_RELAXED, __HIP_MEMORY_SCOPE_AGENT);
                va2 = __hip_atomic_load((const u64*)(s + 8),  __ATOMIC_RELAXED, __HIP_MEMORY_SCOPE_AGENT);
                va3 = __hip_atomic_load((const u64*)(s + 12), __ATOMIC_RELAXED, __HIP_MEMORY_SCOPE_AGENT);
                #pragma unroll
                for (int j = 0; j < 8; ++j)
                    bnB[j] = *(const half8*)(bnp + ((((g + 1) << 3) + j) << 5));
            }
            #pragma unroll
            for (int j = 0; j < 8; ++j) {
                const int c = (g << 3) + j;
                half8 a = *(const half8*)(&Ash[m16 * 1032 + (c << 5) + (quad << 3)]);
                acc_r  = __builtin_amdgcn_mfma_f32_16x16x32_f16(a, br[c], acc_r,  0, 0, 0);
                acc_z  = __builtin_amdgcn_mfma_f32_16x16x32_f16(a, bz[c], acc_z,  0, 0, 0);
                acc_hn = __builtin_amdgcn_mfma_f32_16x16x32_f16(a, bnA[j], acc_hn, 0, 0, 0);
            }
            if (g < 3) {
                #pragma unroll
                for (int j = 0; j < 8; ++j) bnA[j] = bnB[j];
            }
        }

        float pv[4];
        #pragma unroll
        for (int i = 0; i < 4; ++i) {
            float rg = fast_sigmoid(acc_r[i]);
            float zg = fast_sigmoid(acc_z[i]);
            float ng = fast_tanh(acc_in[i] + rg * acc_hn[i]);
            float hn2 = (1.f - zg) * ng + zg * hreg[i];
            hreg[i] = hn2;
            pv[i] = hn2 * wo_u;
            Hsh[(w << 8) + ((quad << 2) + i) * 16 + m16] = (_Float16)hn2;
        }
        __threadfence_block();
        {
            u64 hv = *(const u64*)(&Hsh[(w << 8) + prow * 16 + (pc4 << 2)]);
            __hip_atomic_store(
                (u64*)(hdst + ((size_t)(pi16 + prow) << 10) + (qi << 6) + (w << 4) + (pc4 << 2)),
                hv, __ATOMIC_RELAXED, __HIP_MEMORY_SCOPE_AGENT);
        }
        #pragma unroll
        for (int m = 1; m < 16; m <<= 1) {
            #pragma unroll
            for (int i = 0; i < 4; ++i) pv[i] += __shfl_xor(pv[i], m);
        }
        asm volatile("s_waitcnt vmcnt(0)" ::: "memory");
        __syncthreads();
        if (tid == 0)
            __hip_atomic_store(flag_self, (unsigned)(t + 1),
                               __ATOMIC_RELAXED, __HIP_MEMORY_SCOPE_AGENT);
        if (m16 == 0) {
            #pragma unroll
            for (int i = 0; i < 4; ++i)
                partials[((size_t)(t << 6) + (qi << 2) + w) * 256 + pi16 + (quad << 2) + i] = pv[i];
        }
    }
}

// ---------------- final reduce (coalesced over transposed partials) --------
__global__ void out_reduce(const float* __restrict__ partials, const float* __restrict__ bo,
                           float* __restrict__ out) {
    int t = blockIdx.x, r = threadIdx.x;
    float s = 0.f;
    #pragma unroll
    for (int k = 0; k < 64; ++k) s += partials[((size_t)(t << 6) + k) * 256 + r];
    out[(size_t)r * T_ + t] = s + bo[0];
}

extern "C" void kernel_launch(void* const* d_in, const int* in_sizes, int n_in,
                              void* d_out, int out_size, void* d_ws, size_t ws_size,
                              hipStream_t stream) {
    const float* lag  = (const float*)d_in[0];
    const float* curr = (const float*)d_in[1];
    const float* W1   = (const float*)d_in[2];
    const float* b1   = (const float*)d_in[3];
    const float* W2   = (const float*)d_in[4];
    const float* b2   = (const float*)d_in[5];
    const float* W3   = (const float*)d_in[6];
    const float* b3   = (const float*)d_in[7];
    const float* Wih  = (const float*)d_in[8];
    const float* Whh  = (const float*)d_in[9];
    const float* bih  = (const float*)d_in[10];
    const float* bhh  = (const float*)d_in[11];
    const float* Wo   = (const float*)d_in[12];
    const float* bo   = (const float*)d_in[13];
    float* out = (float*)d_out;

    char* ws = (char*)d_ws;
    size_t off = 0;
    auto alloc = [&](size_t bytes) -> void* {
        void* p = ws + off;
        off += (bytes + 255) & ~(size_t)255;
        return p;
    };
    _Float16* whh16 = (_Float16*)alloc((size_t)3 * H_ * H_ * 2);
    _Float16* wih16 = (_Float16*)alloc((size_t)3 * H_ * WS_ * 2);
    _Float16* x16   = (_Float16*)alloc((size_t)T_ * B_ * WS_ * 2);
    float* hprev32  = (float*)alloc((size_t)B_ * H_ * 4);
    float* partials = (float*)alloc((size_t)T_ * B_ * 64 * 4);
    unsigned* bar   = (unsigned*)alloc(81920);

    const size_t slot_bytes = (size_t)B_ * H_ * 2;
    const size_t ring_bytes = (size_t)(T_ + 1) * slot_bytes;   // 169 slots, ~88.6 MB
    const bool ring_mode = (ws_size >= off + ring_bytes + 4096);
    _Float16* hring = (_Float16*)alloc(ring_mode ? ring_bytes : 4 * slot_bytes);

    hipMemsetAsync(bar, 0, 81920, stream);
    if (ring_mode) {
        // poison slots 1..168 (slot 0 is fully written by enc_fused)
        hipMemsetAsync((char*)hring + slot_bytes, 0xFF, ring_bytes - slot_bytes, stream);
    }

    const int na = 3 * H_ * H_ / 4;
    const int nb = 3 * H_ * WS_ / 4;
    const int nc = T_ * B_ * WS_ / 4;
    const int ntot = na + nb + nc;
    cvt_all<<<(ntot + 255) / 256, 256, 0, stream>>>(
        (const float4*)Whh, (half4*)whh16, na,
        (const float4*)Wih, (half4*)wih16, nb,
        (const float4*)curr, (half4*)x16, nc);

    enc_fused<<<B_, 256, 0, stream>>>(lag, W1, b1, W2, b2, W3, b3, hprev32, hring);

    if (ring_mode)
        gru_hybrid<<<dim3(256), dim3(256), 0, stream>>>(
            hring, hprev32, whh16, wih16, x16, bih, bhh, Wo, partials, bar);
    else
        gru_flags<<<dim3(256), dim3(256), 0, stream>>>(
            hring, hprev32, whh16, wih16, x16, bih, bhh, Wo, partials, bar);

    out_reduce<<<T_, B_, 0, stream>>>(partials, bo, out);
}

// Round 9
// 778.365 us; speedup vs baseline: 1.5188x; 1.0452x over previous
//
#include <hip/hip_runtime.h>
#include <hip/hip_bf16.h>
#include <cstdint>
#include <cstddef>

typedef _Float16 half8 __attribute__((ext_vector_type(8)));
typedef _Float16 half4 __attribute__((ext_vector_type(4)));
typedef float floatx4 __attribute__((ext_vector_type(4)));
typedef unsigned long long u64;

#define B_ 256
#define T_ 168
#define H_ 1024
#define WS_ 64
#define LAG_ 168
#define LAT_ 128
#define SENT 0xFFFFFFFFFFFFFFFFull

__device__ __forceinline__ float fast_sigmoid(float x) {
    return __builtin_amdgcn_rcpf(1.f + __expf(-x));
}
__device__ __forceinline__ float fast_tanh(float x) {
    return 1.f - 2.f * __builtin_amdgcn_rcpf(__expf(2.f * x) + 1.f);
}

// ---------------- fp32 -> fp16 conversion (merged: 3 buffers, 1 launch) ----
__global__ void cvt_all(const float4* __restrict__ a, half4* __restrict__ da, int na,
                        const float4* __restrict__ b, half4* __restrict__ db, int nb,
                        const float4* __restrict__ c, half4* __restrict__ dc, int nc) {
    int i = blockIdx.x * blockDim.x + threadIdx.x;
    const float4* s;
    half4* d;
    int j = i;
    if (j < na) { s = a; d = da; }
    else {
        j -= na;
        if (j < nb) { s = b; d = db; }
        else {
            j -= nb;
            if (j >= nc) return;
            s = c; d = dc;
        }
    }
    float4 v = s[j];
    half4 o;
    o[0] = (_Float16)v.x; o[1] = (_Float16)v.y;
    o[2] = (_Float16)v.z; o[3] = (_Float16)v.w;
    d[j] = o;
}

// ---------------- fused encoder: lag -> 64 -> 128 -> 1024 (one kernel) -----
__global__ void enc_fused(const float* __restrict__ lag,
                          const float* __restrict__ W1, const float* __restrict__ b1,
                          const float* __restrict__ W2, const float* __restrict__ b2,
                          const float* __restrict__ W3, const float* __restrict__ b3,
                          float* __restrict__ hprev32, _Float16* __restrict__ h0f16) {
    __shared__ float lrow[LAG_];
    __shared__ float l1[64];
    __shared__ float l2[LAT_];
    const int r = blockIdx.x, tid = threadIdx.x;
    if (tid < LAG_) lrow[tid] = lag[(size_t)r * LAG_ + tid];
    __syncthreads();
    if (tid < 64) {
        const float* w = W1 + (size_t)tid * LAG_;
        float s = b1[tid];
        for (int k = 0; k < LAG_; ++k) s += lrow[k] * w[k];
        l1[tid] = (s >= 0.f) ? s : 0.01f * s;
    }
    __syncthreads();
    if (tid < LAT_) {
        const float* w = W2 + (size_t)tid * 64;
        float s = b2[tid];
        for (int k = 0; k < 64; ++k) s += l1[k] * w[k];
        l2[tid] = (s >= 0.f) ? s : 0.01f * s;
    }
    __syncthreads();
    for (int j = tid; j < H_; j += 256) {
        const float* w = W3 + (size_t)j * LAT_;
        float acc = b3[j];
        #pragma unroll 8
        for (int k = 0; k < LAT_; ++k) acc += l2[k] * w[k];
        hprev32[(size_t)r * H_ + j] = acc;
        h0f16[(size_t)r * H_ + j]   = (_Float16)acc;
    }
}

// ---------------- R18: R13 loop, drain-free publish (sentinel-validated) ----
// R17 evidence: consumers arrive EARLY (speculative prefetch always saw
// poison) -> critical path is producer-side: publish -> explicit vmcnt(0)
// drain -> __syncthreads (compiler emits ANOTHER implicit vmcnt(0) drain
// before s_barrier) -> flag. Two serialized store-drain RTTs per step.
// Fix: write-once poisoned ring (R15-verified) means the flag need not
// guarantee data visibility — consumers validate staged u64s vs SENT and
// re-load only missing ones (window = store propagation ~300ns; bounded;
// NOT R15's storm which spanned whole producer compute). Therefore:
//   - per-wave flags (R9 scheme, measured ~= per-block): flag store follows
//     publish stores in program order, NO vmcnt(0), NO end-of-step barrier.
//   - consumer: R13's 4-phase flag-gated loop + sentinel-validate at write.
// Hazards: 4 in-loop barriers still order Ash staging; phase regions
// disjoint; cross-step Ash reuse transitively ordered by the flag protocol
// (phase-0 wait needs all group waves' flags=t+1, which follow their phase-3
// Ash reads in program order); Hsh per-wave-private. R9 threadfence kept.
__global__ __launch_bounds__(256, 1) void gru_ring(
    _Float16* __restrict__ hring,
    const float* __restrict__ hprev32, const _Float16* __restrict__ whh16,
    const _Float16* __restrict__ wih16, const _Float16* __restrict__ x16,
    const float* __restrict__ bih, const float* __restrict__ bhh,
    const float* __restrict__ Wo, float* __restrict__ partials,
    unsigned* __restrict__ bar)
{
    __shared__ __align__(16) _Float16 Ash[16 * 1032];
    __shared__ __align__(16) _Float16 Wsh[192 * 72];
    __shared__ __align__(16) _Float16 Hsh[4 * 256];

    const int tid  = threadIdx.x;
    const int w    = tid >> 6;
    const int lane = tid & 63;
    const int m16  = lane & 15;
    const int quad = lane >> 4;
    const int pi   = blockIdx.x & 15;
    const int qi   = blockIdx.x >> 4;
    const int pi16 = pi << 4;
    const int u    = (qi << 6) + (w << 4) + m16;

    // Wih slice -> LDS (once)
    for (int idx = tid; idx < 1536; idx += 256) {
        int rowl = idx >> 3, ch = idx & 7;
        int g = rowl >> 6, ru = rowl & 63;
        *(uint4*)(&Wsh[rowl * 72 + (ch << 3)]) =
            *(const uint4*)(wih16 + (size_t)(((g << 10) + (qi << 6) + ru) << 6) + (ch << 3));
    }

    // Resident Whh: r,z gates (AGPR-backed); n streamed per phase
    half8 br[32], bz[32];
    {
        const _Float16* p0 = whh16 + ((size_t)u << 10) + (quad << 3);
        const _Float16* p1 = whh16 + ((size_t)(H_ + u) << 10) + (quad << 3);
        #pragma unroll
        for (int c = 0; c < 32; ++c) br[c] = *(const half8*)(p0 + (c << 5));
        #pragma unroll
        for (int c = 0; c < 32; ++c) bz[c] = *(const half8*)(p1 + (c << 5));
    }
    const _Float16* bnp = whh16 + ((size_t)(2 * H_ + u) << 10) + (quad << 3);

    const float b_r  = bih[u]          + bhh[u];
    const float b_z  = bih[H_ + u]     + bhh[H_ + u];
    const float b_in = bih[2 * H_ + u];
    const float b_hn = bhh[2 * H_ + u];
    const float wo_u = Wo[u];

    float hreg[4];
    #pragma unroll
    for (int i = 0; i < 4; ++i)
        hreg[i] = hprev32[((size_t)(pi16 + (quad << 2) + i) << 10) + u];

    __syncthreads();

    // PER-WAVE flag lines (64B apart): flag of (block pi|qi, wave w)
    unsigned* flag_self       = bar + ((((pi << 4) | qi) << 2 | w) << 4);
    const unsigned* flag_peer = bar + ((((pi << 4) | (lane >> 2)) << 2 | (lane & 3)) << 4);
    const int srow = tid >> 4;     // staging: this thread's local row
    const int sch  = tid & 15;     // 32B chunk (16 units)
    const int prow = lane >> 2;    // publish: row, 8B chunk
    const int pc4  = lane & 3;

    for (int t = 0; t < T_; ++t) {
        const _Float16* hsrc = hring + (size_t)t * (B_ * H_);
        _Float16*       hdst = hring + (size_t)(t + 1) * (B_ * H_);

        // h-independent prefetch
        half8 ax0 = *(const half8*)(x16 + (((size_t)t << 8) + pi16 + m16) * WS_ + (quad << 3));
        half8 ax1 = *(const half8*)(x16 + (((size_t)t << 8) + pi16 + m16) * WS_ + 32 + (quad << 3));
        half8 bnA[8], bnB[8];
        #pragma unroll
        for (int j = 0; j < 8; ++j) bnA[j] = *(const half8*)(bnp + (j << 5));

        const unsigned need = (unsigned)t;
        u64 rdy = 0;
        const _Float16* sbase = hsrc + ((size_t)(pi16 + srow) << 10) + (sch << 4);

        // wait phase 0: lanes 0..15 = waves of producer blocks qi'=0..3
        while ((rdy & 0xFFFFull) != 0xFFFFull) {
            unsigned f = __hip_atomic_load(flag_peer, __ATOMIC_RELAXED, __HIP_MEMORY_SCOPE_AGENT);
            rdy |= __ballot(f >= need);
            if ((rdy & 0xFFFFull) != 0xFFFFull) __builtin_amdgcn_s_sleep(1);
        }
        // issue phase-0 loads
        u64 va0, va1, va2, va3;
        va0 = __hip_atomic_load((const u64*)(sbase + 0),  __ATOMIC_RELAXED, __HIP_MEMORY_SCOPE_AGENT);
        va1 = __hip_atomic_load((const u64*)(sbase + 4),  __ATOMIC_RELAXED, __HIP_MEMORY_SCOPE_AGENT);
        va2 = __hip_atomic_load((const u64*)(sbase + 8),  __ATOMIC_RELAXED, __HIP_MEMORY_SCOPE_AGENT);
        va3 = __hip_atomic_load((const u64*)(sbase + 12), __ATOMIC_RELAXED, __HIP_MEMORY_SCOPE_AGENT);

        floatx4 acc_r  = {b_r,  b_r,  b_r,  b_r };
        floatx4 acc_z  = {b_z,  b_z,  b_z,  b_z };
        floatx4 acc_in = {b_in, b_in, b_in, b_in};
        floatx4 acc_hn = {b_hn, b_hn, b_hn, b_hn};

        // gi = x_t @ Wih^T (hides phase-0 load flight)
        {
            half8 p0 = *(const half8*)(&Wsh[((w << 4) + m16) * 72        + (quad << 3)]);
            half8 p1 = *(const half8*)(&Wsh[(64 + (w << 4) + m16) * 72   + (quad << 3)]);
            half8 p2 = *(const half8*)(&Wsh[(128 + (w << 4) + m16) * 72  + (quad << 3)]);
            acc_r  = __builtin_amdgcn_mfma_f32_16x16x32_f16(ax0, p0, acc_r,  0, 0, 0);
            acc_z  = __builtin_amdgcn_mfma_f32_16x16x32_f16(ax0, p1, acc_z,  0, 0, 0);
            acc_in = __builtin_amdgcn_mfma_f32_16x16x32_f16(ax0, p2, acc_in, 0, 0, 0);
            half8 q0 = *(const half8*)(&Wsh[((w << 4) + m16) * 72        + 32 + (quad << 3)]);
            half8 q1 = *(const half8*)(&Wsh[(64 + (w << 4) + m16) * 72   + 32 + (quad << 3)]);
            half8 q2 = *(const half8*)(&Wsh[(128 + (w << 4) + m16) * 72  + 32 + (quad << 3)]);
            acc_r  = __builtin_amdgcn_mfma_f32_16x16x32_f16(ax1, q0, acc_r,  0, 0, 0);
            acc_z  = __builtin_amdgcn_mfma_f32_16x16x32_f16(ax1, q1, acc_z,  0, 0, 0);
            acc_in = __builtin_amdgcn_mfma_f32_16x16x32_f16(ax1, q2, acc_in, 0, 0, 0);
        }

        // 4 phases: validate staged (sentinel, short window) -> write ->
        //           barrier -> wait+issue next phase -> MFMA this phase
        #pragma unroll
        for (int g = 0; g < 4; ++g) {
            // sentinel validation: flag preceded data only by propagation skew;
            // re-load just the missing u64s (no storm: window ~ store latency)
            for (;;) {
                bool miss = (va0 == SENT) | (va1 == SENT) | (va2 == SENT) | (va3 == SENT);
                if (!__any(miss)) break;
                const _Float16* sp = sbase + (g << 8);
                if (va0 == SENT) va0 = __hip_atomic_load((const u64*)(sp + 0),  __ATOMIC_RELAXED, __HIP_MEMORY_SCOPE_AGENT);
                if (va1 == SENT) va1 = __hip_atomic_load((const u64*)(sp + 4),  __ATOMIC_RELAXED, __HIP_MEMORY_SCOPE_AGENT);
                if (va2 == SENT) va2 = __hip_atomic_load((const u64*)(sp + 8),  __ATOMIC_RELAXED, __HIP_MEMORY_SCOPE_AGENT);
                if (va3 == SENT) va3 = __hip_atomic_load((const u64*)(sp + 12), __ATOMIC_RELAXED, __HIP_MEMORY_SCOPE_AGENT);
            }
            {
                _Float16* d = &Ash[srow * 1032 + (g << 8) + (sch << 4)];
                *(u64*)(d + 0)  = va0;
                *(u64*)(d + 4)  = va1;
                *(u64*)(d + 8)  = va2;
                *(u64*)(d + 12) = va3;
            }
            __syncthreads();
            if (g < 3) {
                const u64 mask = 0xFFFFull << ((g + 1) << 4);
                while ((rdy & mask) != mask) {
                    unsigned f = __hip_atomic_load(flag_peer, __ATOMIC_RELAXED, __HIP_MEMORY_SCOPE_AGENT);
                    rdy |= __ballot(f >= need);
                    if ((rdy & mask) != mask) __builtin_amdgcn_s_sleep(1);
                }
                const _Float16* sn = sbase + ((g + 1) << 8);
                va0 = __hip_atomic_load((const u64*)(sn + 0),  __ATOMIC_RELAXED, __HIP_MEMORY_SCOPE_AGENT);
                va1 = __hip_atomic_load((const u64*)(sn + 4),  __ATOMIC_RELAXED, __HIP_MEMORY_SCOPE_AGENT);
                va2 = __hip_atomic_load((const u64*)(sn + 8),  __ATOMIC_RELAXED, __HIP_MEMORY_SCOPE_AGENT);
                va3 = __hip_atomic_load((const u64*)(sn + 12), __ATOMIC_RELAXED, __HIP_MEMORY_SCOPE_AGENT);
                #pragma unroll
                for (int j = 0; j < 8; ++j)
                    bnB[j] = *(const half8*)(bnp + ((((g + 1) << 3) + j) << 5));
            }
            #pragma unroll
            for (int j = 0; j < 8; ++j) {
                const int c = (g << 3) + j;
                half8 a = *(const half8*)(&Ash[m16 * 1032 + (c << 5) + (quad << 3)]);
                acc_r  = __builtin_amdgcn_mfma_f32_16x16x32_f16(a, br[c], acc_r,  0, 0, 0);
                acc_z  = __builtin_amdgcn_mfma_f32_16x16x32_f16(a, bz[c], acc_z,  0, 0, 0);
                acc_hn = __builtin_amdgcn_mfma_f32_16x16x32_f16(a, bnA[j], acc_hn, 0, 0, 0);
            }
            if (g < 3) {
                #pragma unroll
                for (int j = 0; j < 8; ++j) bnA[j] = bnB[j];
            }
        }

        // epilogue: drain-free publish. Per-wave flag follows publish stores
        // in program order (no vmcnt, no barrier); consumers sentinel-validate.
        float pv[4];
        #pragma unroll
        for (int i = 0; i < 4; ++i) {
            float rg = fast_sigmoid(acc_r[i]);
            float zg = fast_sigmoid(acc_z[i]);
            float ng = fast_tanh(acc_in[i] + rg * acc_hn[i]);
            float hn2 = (1.f - zg) * ng + zg * hreg[i];
            hreg[i] = hn2;
            pv[i] = hn2 * wo_u;
            Hsh[(w << 8) + ((quad << 2) + i) * 16 + m16] = (_Float16)hn2;
        }
        __threadfence_block();   // order f16 Hsh writes before the u64 read
        {
            u64 hv = *(const u64*)(&Hsh[(w << 8) + prow * 16 + (pc4 << 2)]);
            __hip_atomic_store(
                (u64*)(hdst + ((size_t)(pi16 + prow) << 10) + (qi << 6) + (w << 4) + (pc4 << 2)),
                hv, __ATOMIC_RELAXED, __HIP_MEMORY_SCOPE_AGENT);
        }
        if (lane == 0)
            __hip_atomic_store(flag_self, (unsigned)(t + 1),
                               __ATOMIC_RELAXED, __HIP_MEMORY_SCOPE_AGENT);
        #pragma unroll
        for (int m = 1; m < 16; m <<= 1) {
            #pragma unroll
            for (int i = 0; i < 4; ++i) pv[i] += __shfl_xor(pv[i], m);
        }
        if (m16 == 0) {
            #pragma unroll
            for (int i = 0; i < 4; ++i)
                partials[((size_t)(t << 6) + (qi << 2) + w) * 256 + pi16 + (quad << 2) + i] = pv[i];
        }
    }
}

// ---------------- fallback: verified R13 flag-based GRU (698us) ------------
__global__ __launch_bounds__(256, 1) void gru_flags(
    _Float16* __restrict__ hbuf,
    const float* __restrict__ hprev32, const _Float16* __restrict__ whh16,
    const _Float16* __restrict__ wih16, const _Float16* __restrict__ x16,
    const float* __restrict__ bih, const float* __restrict__ bhh,
    const float* __restrict__ Wo, float* __restrict__ partials,
    unsigned* __restrict__ bar)
{
    __shared__ __align__(16) _Float16 Ash[16 * 1032];
    __shared__ __align__(16) _Float16 Wsh[192 * 72];
    __shared__ __align__(16) _Float16 Hsh[4 * 256];

    const int tid  = threadIdx.x;
    const int w    = tid >> 6;
    const int lane = tid & 63;
    const int m16  = lane & 15;
    const int quad = lane >> 4;
    const int pi   = blockIdx.x & 15;
    const int qi   = blockIdx.x >> 4;
    const int pi16 = pi << 4;
    const int u    = (qi << 6) + (w << 4) + m16;

    for (int idx = tid; idx < 1536; idx += 256) {
        int rowl = idx >> 3, ch = idx & 7;
        int g = rowl >> 6, ru = rowl & 63;
        *(uint4*)(&Wsh[rowl * 72 + (ch << 3)]) =
            *(const uint4*)(wih16 + (size_t)(((g << 10) + (qi << 6) + ru) << 6) + (ch << 3));
    }

    half8 br[32], bz[32];
    {
        const _Float16* p0 = whh16 + ((size_t)u << 10) + (quad << 3);
        const _Float16* p1 = whh16 + ((size_t)(H_ + u) << 10) + (quad << 3);
        #pragma unroll
        for (int c = 0; c < 32; ++c) br[c] = *(const half8*)(p0 + (c << 5));
        #pragma unroll
        for (int c = 0; c < 32; ++c) bz[c] = *(const half8*)(p1 + (c << 5));
    }
    const _Float16* bnp = whh16 + ((size_t)(2 * H_ + u) << 10) + (quad << 3);

    const float b_r  = bih[u]          + bhh[u];
    const float b_z  = bih[H_ + u]     + bhh[H_ + u];
    const float b_in = bih[2 * H_ + u];
    const float b_hn = bhh[2 * H_ + u];
    const float wo_u = Wo[u];

    float hreg[4];
    #pragma unroll
    for (int i = 0; i < 4; ++i)
        hreg[i] = hprev32[((size_t)(pi16 + (quad << 2) + i) << 10) + u];

    __syncthreads();

    unsigned* flag_self       = bar + (((pi << 4) | qi) << 4);
    const unsigned* flag_peer = bar + (((pi << 4) | (lane & 15)) << 4);
    const int srow = tid >> 4;
    const int sch  = tid & 15;
    const int prow = lane >> 2;
    const int pc4  = lane & 3;

    for (int t = 0; t < T_; ++t) {
        const _Float16* hsrc = hbuf + (size_t)(t & 3) * (B_ * H_);
        _Float16*       hdst = hbuf + (size_t)((t + 1) & 3) * (B_ * H_);

        half8 ax0 = *(const half8*)(x16 + (((size_t)t << 8) + pi16 + m16) * WS_ + (quad << 3));
        half8 ax1 = *(const half8*)(x16 + (((size_t)t << 8) + pi16 + m16) * WS_ + 32 + (quad << 3));
        half8 bnA[8], bnB[8];
        #pragma unroll
        for (int j = 0; j < 8; ++j) bnA[j] = *(const half8*)(bnp + (j << 5));

        const unsigned need = (unsigned)t;
        u64 rdy = 0;

        while ((rdy & 0xFull) != 0xFull) {
            unsigned f = 0;
            if (lane < 16)
                f = __hip_atomic_load(flag_peer, __ATOMIC_RELAXED, __HIP_MEMORY_SCOPE_AGENT);
            rdy |= __ballot(f >= need);
            if ((rdy & 0xFull) != 0xFull) __builtin_amdgcn_s_sleep(1);
        }
        u64 va0, va1, va2, va3;
        {
            const _Float16* s = hsrc + ((size_t)(pi16 + srow) << 10) + (sch << 4);
            va0 = __hip_atomic_load((const u64*)(s + 0),  __ATOMIC_RELAXED, __HIP_MEMORY_SCOPE_AGENT);
            va1 = __hip_atomic_load((const u64*)(s + 4),  __ATOMIC_RELAXED, __HIP_MEMORY_SCOPE_AGENT);
            va2 = __hip_atomic_load((const u64*)(s + 8),  __ATOMIC_RELAXED, __HIP_MEMORY_SCOPE_AGENT);
            va3 = __hip_atomic_load((const u64*)(s + 12), __ATOMIC_RELAXED, __HIP_MEMORY_SCOPE_AGENT);
        }

        floatx4 acc_r  = {b_r,  b_r,  b_r,  b_r };
        floatx4 acc_z  = {b_z,  b_z,  b_z,  b_z };
        floatx4 acc_in = {b_in, b_in, b_in, b_in};
        floatx4 acc_hn = {b_hn, b_hn, b_hn, b_hn};

        {
            half8 p0 = *(const half8*)(&Wsh[((w << 4) + m16) * 72        + (quad << 3)]);
            half8 p1 = *(const half8*)(&Wsh[(64 + (w << 4) + m16) * 72   + (quad << 3)]);
            half8 p2 = *(const half8*)(&Wsh[(128 + (w << 4) + m16) * 72  + (quad << 3)]);
            acc_r  = __builtin_amdgcn_mfma_f32_16x16x32_f16(ax0, p0, acc_r,  0, 0, 0);
            acc_z  = __builtin_amdgcn_mfma_f32_16x16x32_f16(ax0, p1, acc_z,  0, 0, 0);
            acc_in = __builtin_amdgcn_mfma_f32_16x16x32_f16(ax0, p2, acc_in, 0, 0, 0);
            half8 q0 = *(const half8*)(&Wsh[((w << 4) + m16) * 72        + 32 + (quad << 3)]);
            half8 q1 = *(const half8*)(&Wsh[(64 + (w << 4) + m16) * 72   + 32 + (quad << 3)]);
            half8 q2 = *(const half8*)(&Wsh[(128 + (w << 4) + m16) * 72  + 32 + (quad << 3)]);
            acc_r  = __builtin_amdgcn_mfma_f32_16x16x32_f16(ax1, q0, acc_r,  0, 0, 0);
            acc_z  = __builtin_amdgcn_mfma_f32_16x16x32_f16(ax1, q1, acc_z,  0, 0, 0);
            acc_in = __builtin_amdgcn_mfma_f32_16x16x32_f16(ax1, q2, acc_in, 0, 0, 0);
        }

        #pragma unroll
        for (int g = 0; g < 4; ++g) {
            {
                _Float16* d = &Ash[srow * 1032 + (g << 8) + (sch << 4)];
                *(u64*)(d + 0)  = va0;
                *(u64*)(d + 4)  = va1;
                *(u64*)(d + 8)  = va2;
                *(u64*)(d + 12) = va3;
            }
            __syncthreads();
            if (g < 3) {
                const u64 mask = 0xFull << ((g + 1) << 2);
                while ((rdy & mask) != mask) {
                    unsigned f = 0;
                    if (lane < 16)
                        f = __hip_atomic_load(flag_peer, __ATOMIC_RELAXED, __HIP_MEMORY_SCOPE_AGENT);
                    rdy |= __ballot(f >= need);
                    if ((rdy & mask) != mask) __builtin_amdgcn_s_sleep(1);
                }
                const _Float16* s = hsrc + ((size_t)(pi16 + srow) << 10) + ((g + 1) << 8) + (sch << 4);
                va0 = __hip_atomic_load((const u64*)(s + 0),  __ATOMIC_RELAXED, __HIP_MEMORY_SCOPE_AGENT);
                va1 = __hip_atomic_load((const u64*)(s + 4),  __ATOMIC_RELAXED, __HIP_MEMORY_SCOPE_AGENT);
                va2 = __hip_atomic_load((const u64*)(s + 8),  __ATOMIC_RELAXED, __HIP_MEMORY_SCOPE_AGENT);
                va3 = __hip_atomic_load((const u64*)(s + 12), __ATOMIC_RELAXED, __HIP_MEMORY_SCOPE_AGENT);
                #pragma unroll
                for (int j = 0; j < 8; ++j)
                    bnB[j] = *(const half8*)(bnp + ((((g + 1) << 3) + j) << 5));
            }
            #pragma unroll
            for (int j = 0; j < 8; ++j) {
                const int c = (g << 3) + j;
                half8 a = *(const half8*)(&Ash[m16 * 1032 + (c << 5) + (quad << 3)]);
                acc_r  = __builtin_amdgcn_mfma_f32_16x16x32_f16(a, br[c], acc_r,  0, 0, 0);
                acc_z  = __builtin_amdgcn_mfma_f32_16x16x32_f16(a, bz[c], acc_z,  0, 0, 0);
                acc_hn = __builtin_amdgcn_mfma_f32_16x16x32_f16(a, bnA[j], acc_hn, 0, 0, 0);
            }
            if (g < 3) {
                #pragma unroll
                for (int j = 0; j < 8; ++j) bnA[j] = bnB[j];
            }
        }

        float pv[4];
        #pragma unroll
        for (int i = 0; i < 4; ++i) {
            float rg = fast_sigmoid(acc_r[i]);
            float zg = fast_sigmoid(acc_z[i]);
            float ng = fast_tanh(acc_in[i] + rg * acc_hn[i]);
            float hn2 = (1.f - zg) * ng + zg * hreg[i];
            hreg[i] = hn2;
            pv[i] = hn2 * wo_u;
            Hsh[(w << 8) + ((quad << 2) + i) * 16 + m16] = (_Float16)hn2;
        }
        __threadfence_block();
        {
            u64 hv = *(const u64*)(&Hsh[(w << 8) + prow * 16 + (pc4 << 2)]);
            __hip_atomic_store(
                (u64*)(hdst + ((size_t)(pi16 + prow) << 10) + (qi << 6) + (w << 4) + (pc4 << 2)),
                hv, __ATOMIC_RELAXED, __HIP_MEMORY_SCOPE_AGENT);
        }
        #pragma unroll
        for (int m = 1; m < 16; m <<= 1) {
            #pragma unroll
            for (int i = 0; i < 4; ++i) pv[i] += __shfl_xor(pv[i], m);
        }
        asm volatile("s_waitcnt vmcnt(0)" ::: "memory");
        __syncthreads();
        if (tid == 0)
            __hip_atomic_store(flag_self, (unsigned)(t + 1),
                               __ATOMIC_RELAXED, __HIP_MEMORY_SCOPE_AGENT);
        if (m16 == 0) {
            #pragma unroll
            for (int i = 0; i < 4; ++i)
                partials[((size_t)(t << 6) + (qi << 2) + w) * 256 + pi16 + (quad << 2) + i] = pv[i];
        }
    }
}

// ---------------- final reduce (coalesced over transposed partials) --------
__global__ void out_reduce(const float* __restrict__ partials, const float* __restrict__ bo,
                           float* __restrict__ out) {
    int t = blockIdx.x, r = threadIdx.x;
    float s = 0.f;
    #pragma unroll
    for (int k = 0; k < 64; ++k) s += partials[((size_t)(t << 6) + k) * 256 + r];
    out[(size_t)r * T_ + t] = s + bo[0];
}

extern "C" void kernel_launch(void* const* d_in, const int* in_sizes, int n_in,
                              void* d_out, int out_size, void* d_ws, size_t ws_size,
                              hipStream_t stream) {
    const float* lag  = (const float*)d_in[0];
    const float* curr = (const float*)d_in[1];
    const float* W1   = (const float*)d_in[2];
    const float* b1   = (const float*)d_in[3];
    const float* W2   = (const float*)d_in[4];
    const float* b2   = (const float*)d_in[5];
    const float* W3   = (const float*)d_in[6];
    const float* b3   = (const float*)d_in[7];
    const float* Wih  = (const float*)d_in[8];
    const float* Whh  = (const float*)d_in[9];
    const float* bih  = (const float*)d_in[10];
    const float* bhh  = (const float*)d_in[11];
    const float* Wo   = (const float*)d_in[12];
    const float* bo   = (const float*)d_in[13];
    float* out = (float*)d_out;

    char* ws = (char*)d_ws;
    size_t off = 0;
    auto alloc = [&](size_t bytes) -> void* {
        void* p = ws + off;
        off += (bytes + 255) & ~(size_t)255;
        return p;
    };
    _Float16* whh16 = (_Float16*)alloc((size_t)3 * H_ * H_ * 2);
    _Float16* wih16 = (_Float16*)alloc((size_t)3 * H_ * WS_ * 2);
    _Float16* x16   = (_Float16*)alloc((size_t)T_ * B_ * WS_ * 2);
    float* hprev32  = (float*)alloc((size_t)B_ * H_ * 4);
    float* partials = (float*)alloc((size_t)T_ * B_ * 64 * 4);
    unsigned* bar   = (unsigned*)alloc(81920);

    const size_t slot_bytes = (size_t)B_ * H_ * 2;
    const size_t ring_bytes = (size_t)(T_ + 1) * slot_bytes;   // 169 slots, ~88.6 MB
    const bool ring_mode = (ws_size >= off + ring_bytes + 4096);
    _Float16* hring = (_Float16*)alloc(ring_mode ? ring_bytes : 4 * slot_bytes);

    hipMemsetAsync(bar, 0, 81920, stream);
    if (ring_mode) {
        // poison slots 1..168 (slot 0 is fully written by enc_fused)
        hipMemsetAsync((char*)hring + slot_bytes, 0xFF, ring_bytes - slot_bytes, stream);
    }

    const int na = 3 * H_ * H_ / 4;
    const int nb = 3 * H_ * WS_ / 4;
    const int nc = T_ * B_ * WS_ / 4;
    const int ntot = na + nb + nc;
    cvt_all<<<(ntot + 255) / 256, 256, 0, stream>>>(
        (const float4*)Whh, (half4*)whh16, na,
        (const float4*)Wih, (half4*)wih16, nb,
        (const float4*)curr, (half4*)x16, nc);

    enc_fused<<<B_, 256, 0, stream>>>(lag, W1, b1, W2, b2, W3, b3, hprev32, hring);

    if (ring_mode)
        gru_ring<<<dim3(256), dim3(256), 0, stream>>>(
            hring, hprev32, whh16, wih16, x16, bih, bhh, Wo, partials, bar);
    else
        gru_flags<<<dim3(256), dim3(256), 0, stream>>>(
            hring, hprev32, whh16, wih16, x16, bih, bhh, Wo, partials, bar);

    out_reduce<<<T_, B_, 0, stream>>>(partials, bo, out);
}